// Round 4
// baseline (369.023 us; speedup 1.0000x reference)
//
#include <hip/hip_runtime.h>
#include <hip/hip_cooperative_groups.h>
#include <math.h>

namespace cg = cooperative_groups;

#define LSEQ 1024
#define EDIM 512
#define HD 64
#define CCH 32
#define NCH 32
#define DFEAT 128

typedef unsigned short u16;
typedef short bf16x8 __attribute__((ext_vector_type(8)));
typedef float f32x4 __attribute__((ext_vector_type(4)));

__device__ __forceinline__ u16 f2bf(float f) {
    unsigned u = __float_as_uint(f);
    unsigned r = (u + 0x7fffu + ((u >> 16) & 1u)) >> 16;
    return (u16)r;
}
__device__ __forceinline__ float bf2f(u16 x) {
    return __uint_as_float((unsigned)x << 16);
}
__device__ __forceinline__ void async16(void* lds, const void* g) {
    __builtin_amdgcn_global_load_lds(
        (const __attribute__((address_space(1))) unsigned int*)g,
        (__attribute__((address_space(3))) unsigned int*)lds, 16, 0, 0);
}

// ---------------- cast fp32 -> bf16 for X and the 4 weight matrices
__global__ __launch_bounds__(256) void cast_kernel(
    const float* __restrict__ X,  const float* __restrict__ Wq,
    const float* __restrict__ Wk, const float* __restrict__ Wv,
    const float* __restrict__ Wo, u16* __restrict__ Xb, u16* __restrict__ Wb)
{
    int i = blockIdx.x * 256 + threadIdx.x;   // one float4 group per thread
    const float* src; u16* dst; int off;
    if (i < 262144)      { src = X;  dst = Xb;          off = i; }
    else if (i < 327680) { src = Wq; dst = Wb;          off = i - 262144; }
    else if (i < 393216) { src = Wk; dst = Wb + 262144; off = i - 327680; }
    else if (i < 458752) { src = Wv; dst = Wb + 524288; off = i - 393216; }
    else                 { src = Wo; dst = Wb + 786432; off = i - 458752; }
    float4 v = *(const float4*)&src[(size_t)off * 4];
    ushort4 o; o.x = f2bf(v.x); o.y = f2bf(v.y); o.z = f2bf(v.z); o.w = f2bf(v.w);
    *(ushort4*)&dst[(size_t)off * 4] = o;
}

// ---------------- QKV projection via bf16 MFMA, bf16 outputs in head layout
__global__ __launch_bounds__(256) void qkv_mfma_kernel(
    const u16* __restrict__ Xb, const u16* __restrict__ Wb,
    const float* __restrict__ bq, const float* __restrict__ bk, const float* __restrict__ bv,
    u16* __restrict__ qf, u16* __restrict__ kf, u16* __restrict__ vf)
{
    const int z = blockIdx.z;
    const u16* __restrict__ W = Wb + (size_t)z * 262144;
    const float* __restrict__ bias = (z == 0) ? bq : (z == 1) ? bk : bv;
    const int r0 = blockIdx.x * 128;
    const int j0 = blockIdx.y * 128;
    __shared__ u16 As[128 * 32];
    __shared__ u16 Bs[128 * 32];
    const int t = threadIdx.x;
    const int wave = t >> 6, lane = t & 63;
    const int wm = (wave & 1) * 64, wn = (wave >> 1) * 64;
    const int cl = lane & 15, rg4 = lane >> 4;
    f32x4 acc[4][4];
    #pragma unroll
    for (int fi = 0; fi < 4; ++fi)
        #pragma unroll
        for (int fj = 0; fj < 4; ++fj) acc[fi][fj] = (f32x4){0.f, 0.f, 0.f, 0.f};

    for (int kb = 0; kb < 512; kb += 32) {
        #pragma unroll
        for (int i = 0; i < 2; ++i) {
            int chunk = i * 256 + t;
            int row = chunk >> 2, kg = chunk & 3;
            async16(&As[(size_t)(i * 256 + wave * 64) * 8], Xb + (size_t)(r0 + row) * 512 + kb + kg * 8);
            async16(&Bs[(size_t)(i * 256 + wave * 64) * 8], W  + (size_t)(j0 + row) * 512 + kb + kg * 8);
        }
        __syncthreads();
        bf16x8 af[4], bg[4];
        #pragma unroll
        for (int f = 0; f < 4; ++f) {
            af[f] = *(const bf16x8*)&As[(wm + f * 16 + cl) * 32 + rg4 * 8];
            bg[f] = *(const bf16x8*)&Bs[(wn + f * 16 + cl) * 32 + rg4 * 8];
        }
        #pragma unroll
        for (int fi = 0; fi < 4; ++fi)
            #pragma unroll
            for (int fj = 0; fj < 4; ++fj)
                acc[fi][fj] = __builtin_amdgcn_mfma_f32_16x16x32_bf16(af[fi], bg[fj], acc[fi][fj], 0, 0, 0);
        __syncthreads();
    }

    float biasv[4];
    #pragma unroll
    for (int fj = 0; fj < 4; ++fj) biasv[fj] = bias[j0 + wn + fj * 16 + cl];
    #pragma unroll
    for (int fi = 0; fi < 4; ++fi) {
        #pragma unroll
        for (int rr = 0; rr < 4; ++rr) {
            const int row_g = r0 + wm + fi * 16 + rg4 * 4 + rr;
            const int l = row_g >> 1, bb = row_g & 1;
            if (z < 2) {
                float ang = 1.5707963267948966f * (float)(l + 1) * (1.0f / 1024.0f);
                float sv, cv;
                sincosf(ang, &sv, &cv);
                u16* __restrict__ dst = (z == 0) ? qf : kf;
                #pragma unroll
                for (int fj = 0; fj < 4; ++fj) {
                    const int jg = j0 + wn + fj * 16 + cl;
                    float y = fmaxf(acc[fi][fj][rr] + biasv[fj], 0.f);
                    const int h = jg >> 6, d = jg & 63;
                    size_t base = (size_t)((bb * 8 + h) * LSEQ + l) * DFEAT;
                    dst[base + d]      = f2bf(y * sv);
                    dst[base + d + 64] = f2bf(y * cv);
                }
            } else {
                #pragma unroll
                for (int fj = 0; fj < 4; ++fj) {
                    const int jg = j0 + wn + fj * 16 + cl;
                    float y = acc[fi][fj][rr] + biasv[fj];
                    const int h = jg >> 6, d = jg & 63;
                    vf[(size_t)((bb * 8 + h) * LSEQ + l) * HD + d] = f2bf(y);
                }
            }
        }
    }
}

// ---------------- fused mid-chain: chunk sums -> grid sync -> prefix -> grid sync -> attn
__global__ __launch_bounds__(256) void mid_fused_kernel(
    const u16* __restrict__ qf, const u16* __restrict__ kf, const u16* __restrict__ vf,
    float* __restrict__ KVc, float* __restrict__ K1c,
    u16* __restrict__ Spt, float* __restrict__ K1p, u16* __restrict__ Amb)
{
    cg::grid_group grid = cg::this_grid();
    __shared__ union {
        struct {                       // phase 1 (24576 B)
            u16 Ks[32 * 128];          // l-major K chunk
            u16 KT[128 * 32];          // transposed K
            u16 Vs[32 * 64];           // l-major V chunk
            u16 VT[64 * 32];           // transposed V
        } p1;
        struct {                       // phase 3 (24448 B)
            u16 Qs[32 * 136];
            u16 Ks[32 * 136];
            u16 VT[64 * 32];
            u16 Am[32 * 32];
            float K1s[128];
            float dsum2[2][32];
            float qk1[32];
        } p3;
    } sh;
    const int b = blockIdx.x;
    const int n = b >> 5, c = b & 31;
    const int t = threadIdx.x;
    const int wave = t >> 6, lane = t & 63;
    const int cl = lane & 15, rg4 = lane >> 4;

    // ======== phase 1: per-chunk KV sums (MFMA) + K1 sums
    {
        const u16* kbase = kf + (size_t)(n * LSEQ + c * CCH) * DFEAT;
        const u16* vbase = vf + (size_t)(n * LSEQ + c * CCH) * HD;
        #pragma unroll
        for (int i = 0; i < 2; ++i)
            async16(&sh.p1.Ks[(i * 256 + wave * 64) * 8], kbase + (size_t)(i * 256 + t) * 8);
        async16(&sh.p1.Vs[(wave * 64) * 8], vbase + (size_t)t * 8);
        __syncthreads();
        {   // V transpose: thread -> (m = t&63, l0 = (t>>6)*8)
            int m = t & 63, l0 = (t >> 6) * 8;
            u16 tmp[8];
            #pragma unroll
            for (int j = 0; j < 8; ++j) tmp[j] = sh.p1.Vs[(l0 + j) * 64 + m];
            *(bf16x8*)&sh.p1.VT[m * 32 + l0] = *(bf16x8*)tmp;
        }
        {   // K transpose: thread -> (d = t&127, l0 = (t>>7)*16)
            int d = t & 127, l0 = (t >> 7) * 16;
            #pragma unroll
            for (int half = 0; half < 2; ++half) {
                u16 tmp[8];
                #pragma unroll
                for (int j = 0; j < 8; ++j) tmp[j] = sh.p1.Ks[(l0 + half * 8 + j) * 128 + d];
                *(bf16x8*)&sh.p1.KT[d * 32 + l0 + half * 8] = *(bf16x8*)tmp;
            }
        }
        __syncthreads();
        // KVc[m][d] = sum_l V[l][m] * K[l][d]; wave w -> m-tile w, 8 d-tiles
        bf16x8 af = *(const bf16x8*)&sh.p1.VT[(wave * 16 + cl) * 32 + rg4 * 8];
        f32x4 acc[8];
        #pragma unroll
        for (int ni = 0; ni < 8; ++ni) {
            bf16x8 bfr = *(const bf16x8*)&sh.p1.KT[(ni * 16 + cl) * 32 + rg4 * 8];
            acc[ni] = __builtin_amdgcn_mfma_f32_16x16x32_bf16(af, bfr, (f32x4){0.f,0.f,0.f,0.f}, 0, 0, 0);
        }
        float* outp = KVc + (size_t)(n * NCH + c) * (HD * DFEAT);
        #pragma unroll
        for (int ni = 0; ni < 8; ++ni)
            #pragma unroll
            for (int r = 0; r < 4; ++r)
                outp[(size_t)(wave * 16 + rg4 * 4 + r) * 128 + ni * 16 + cl] = acc[ni][r];
        if (t < 128) {
            float s = 0.f;
            #pragma unroll
            for (int g = 0; g < 4; ++g) {
                bf16x8 kv = *(const bf16x8*)&sh.p1.KT[t * 32 + g * 8];
                #pragma unroll
                for (int j = 0; j < 8; ++j) s += bf2f(((u16*)&kv)[j]);
            }
            K1c[(size_t)(n * NCH + c) * DFEAT + t] = s;
        }
    }
    __threadfence();
    grid.sync();

    // ======== phase 2: exclusive prefix over chunks (KV -> bf16 Spt; K1 -> fp32 K1p)
    {
        const int e = c * 256 + t;   // 0..8191 within head n
        const float* src = KVc + (size_t)n * NCH * 8192 + e;
        u16* dst = Spt + (size_t)n * NCH * 8192 + e;
        float v[32];
        #pragma unroll
        for (int cc = 0; cc < 32; ++cc) v[cc] = src[(size_t)cc * 8192];
        float run = 0.f;
        #pragma unroll
        for (int cc = 0; cc < 32; ++cc) { dst[(size_t)cc * 8192] = f2bf(run); run += v[cc]; }
        if (b < 8) {
            const int idx = b * 256 + t;  // 0..2047
            const int nn = idx >> 7, d = idx & 127;
            const float* s2 = K1c + (size_t)nn * NCH * DFEAT + d;
            float* d2 = K1p + (size_t)nn * NCH * DFEAT + d;
            float v2[32];
            #pragma unroll
            for (int cc = 0; cc < 32; ++cc) v2[cc] = s2[cc * DFEAT];
            float run2 = 0.f;
            #pragma unroll
            for (int cc = 0; cc < 32; ++cc) { d2[cc * DFEAT] = run2; run2 += v2[cc]; }
        }
    }
    __threadfence();
    grid.sync();

    // ======== phase 3: intra-chunk attention via MFMA + prefix terms + normalize
    {
        const int mi = wave >> 1, nh = wave & 1;
        const u16* qbase = qf + (size_t)(n * LSEQ + c * CCH) * DFEAT;
        const u16* kbase = kf + (size_t)(n * LSEQ + c * CCH) * DFEAT;
        const u16* vbase = vf + (size_t)(n * LSEQ + c * CCH) * HD;
        const u16* spbase = Spt + (size_t)(n * NCH + c) * 8192;

        // prefetch S_prev B-frags straight from global (16B per lane)
        bf16x8 spf[2][4];
        #pragma unroll
        for (int ni2 = 0; ni2 < 2; ++ni2)
            #pragma unroll
            for (int ks = 0; ks < 4; ++ks)
                spf[ni2][ks] = *(const bf16x8*)&spbase[((2 * nh + ni2) * 16 + cl) * 128 + ks * 32 + rg4 * 8];

        // stage Q,K into padded LDS
        #pragma unroll
        for (int i = 0; i < 2; ++i) {
            int chunk = i * 256 + t;            // 0..511
            int row = chunk >> 4, c8 = chunk & 15;
            *(bf16x8*)&sh.p3.Qs[row * 136 + c8 * 8] = *(const bf16x8*)&qbase[row * 128 + c8 * 8];
            *(bf16x8*)&sh.p3.Ks[row * 136 + c8 * 8] = *(const bf16x8*)&kbase[row * 128 + c8 * 8];
        }
        {   // V transpose (from global, scalar coalesced reads)
            u16 tmp[8];
            #pragma unroll
            for (int j = 0; j < 8; ++j) tmp[j] = vbase[(wave * 8 + j) * HD + lane];
            *(bf16x8*)&sh.p3.VT[lane * 32 + wave * 8] = *(bf16x8*)tmp;
        }
        if (t < 128) sh.p3.K1s[t] = K1p[(size_t)(n * NCH + c) * DFEAT + t];
        __syncthreads();

        // QK^T tile (mi, nh)
        f32x4 a_acc = (f32x4){0.f, 0.f, 0.f, 0.f};
        #pragma unroll
        for (int ks = 0; ks < 4; ++ks) {
            bf16x8 aq = *(const bf16x8*)&sh.p3.Qs[(mi * 16 + cl) * 136 + ks * 32 + rg4 * 8];
            bf16x8 bk = *(const bf16x8*)&sh.p3.Ks[(nh * 16 + cl) * 136 + ks * 32 + rg4 * 8];
            a_acc = __builtin_amdgcn_mfma_f32_16x16x32_bf16(aq, bk, a_acc, 0, 0, 0);
        }
        // mask, fp32 rowsum, write bf16 A
        #pragma unroll
        for (int r = 0; r < 4; ++r) {
            int l_loc = mi * 16 + rg4 * 4 + r;
            int lp_loc = nh * 16 + cl;
            float v = (lp_loc <= l_loc) ? a_acc[r] : 0.f;
            sh.p3.Am[l_loc * 32 + lp_loc] = f2bf(v);
            float s = v;
            s += __shfl_xor(s, 1); s += __shfl_xor(s, 2);
            s += __shfl_xor(s, 4); s += __shfl_xor(s, 8);
            if (cl == 0) sh.p3.dsum2[nh][l_loc] = s;
        }
        {   // q . K1_prev per row: 8 lanes per row, 16 d each
            int row = wave * 8 + (lane >> 3), seg = lane & 7;
            float s = 0.f;
            #pragma unroll
            for (int j = 0; j < 16; ++j) {
                int d = seg * 16 + j;
                s += bf2f(sh.p3.Qs[row * 136 + d]) * sh.p3.K1s[d];
            }
            s += __shfl_xor(s, 1); s += __shfl_xor(s, 2); s += __shfl_xor(s, 4);
            if (seg == 0) sh.p3.qk1[row] = s;
        }
        __syncthreads();

        // C = Q @ S_prev + A_masked @ V   (tiles (mi, 2nh..2nh+1))
        f32x4 oacc[2] = {(f32x4){0.f,0.f,0.f,0.f}, (f32x4){0.f,0.f,0.f,0.f}};
        #pragma unroll
        for (int ks = 0; ks < 4; ++ks) {
            bf16x8 aq = *(const bf16x8*)&sh.p3.Qs[(mi * 16 + cl) * 136 + ks * 32 + rg4 * 8];
            #pragma unroll
            for (int ni2 = 0; ni2 < 2; ++ni2)
                oacc[ni2] = __builtin_amdgcn_mfma_f32_16x16x32_bf16(aq, spf[ni2][ks], oacc[ni2], 0, 0, 0);
        }
        {
            bf16x8 aa = *(const bf16x8*)&sh.p3.Am[(mi * 16 + cl) * 32 + rg4 * 8];
            #pragma unroll
            for (int ni2 = 0; ni2 < 2; ++ni2) {
                bf16x8 bv = *(const bf16x8*)&sh.p3.VT[((2 * nh + ni2) * 16 + cl) * 32 + rg4 * 8];
                oacc[ni2] = __builtin_amdgcn_mfma_f32_16x16x32_bf16(aa, bv, oacc[ni2], 0, 0, 0);
            }
        }
        // normalize + scatter to Amb (bf16, row r = l*2+b, col h*64+m)
        const int bb = n >> 3, h = n & 7;
        #pragma unroll
        for (int r = 0; r < 4; ++r) {
            int l_loc = mi * 16 + rg4 * 4 + r;
            float den = fmaxf(sh.p3.dsum2[0][l_loc] + sh.p3.dsum2[1][l_loc] + sh.p3.qk1[l_loc], 1e-6f);
            float inv = 1.0f / den;
            int rrow = (c * CCH + l_loc) * 2 + bb;
            #pragma unroll
            for (int ni2 = 0; ni2 < 2; ++ni2) {
                int m = (2 * nh + ni2) * 16 + cl;
                Amb[(size_t)rrow * EDIM + h * 64 + m] = f2bf(oacc[ni2][r] * inv);
            }
        }
    }
}

// ---------------- output projection via bf16 MFMA: out = Am @ Wo^T + bo
__global__ __launch_bounds__(256) void out_mfma_kernel(
    const u16* __restrict__ Amb, const u16* __restrict__ Wob,
    const float* __restrict__ bo, float* __restrict__ out)
{
    const int r0 = blockIdx.x * 128;
    const int j0 = blockIdx.y * 128;
    __shared__ u16 As[128 * 32];
    __shared__ u16 Bs[128 * 32];
    const int t = threadIdx.x;
    const int wave = t >> 6, lane = t & 63;
    const int wm = (wave & 1) * 64, wn = (wave >> 1) * 64;
    const int cl = lane & 15, rg4 = lane >> 4;
    f32x4 acc[4][4];
    #pragma unroll
    for (int fi = 0; fi < 4; ++fi)
        #pragma unroll
        for (int fj = 0; fj < 4; ++fj) acc[fi][fj] = (f32x4){0.f, 0.f, 0.f, 0.f};

    for (int kb = 0; kb < 512; kb += 32) {
        #pragma unroll
        for (int i = 0; i < 2; ++i) {
            int chunk = i * 256 + t;
            int row = chunk >> 2, kg = chunk & 3;
            async16(&As[(size_t)(i * 256 + wave * 64) * 8], Amb + (size_t)(r0 + row) * 512 + kb + kg * 8);
            async16(&Bs[(size_t)(i * 256 + wave * 64) * 8], Wob + (size_t)(j0 + row) * 512 + kb + kg * 8);
        }
        __syncthreads();
        bf16x8 af[4], bg[4];
        #pragma unroll
        for (int f = 0; f < 4; ++f) {
            af[f] = *(const bf16x8*)&As[(wm + f * 16 + cl) * 32 + rg4 * 8];
            bg[f] = *(const bf16x8*)&Bs[(wn + f * 16 + cl) * 32 + rg4 * 8];
        }
        #pragma unroll
        for (int fi = 0; fi < 4; ++fi)
            #pragma unroll
            for (int fj = 0; fj < 4; ++fj)
                acc[fi][fj] = __builtin_amdgcn_mfma_f32_16x16x32_bf16(af[fi], bg[fj], acc[fi][fj], 0, 0, 0);
        __syncthreads();
    }

    float bov[4];
    #pragma unroll
    for (int fj = 0; fj < 4; ++fj) bov[fj] = bo[j0 + wn + fj * 16 + cl];
    #pragma unroll
    for (int fi = 0; fi < 4; ++fi)
        #pragma unroll
        for (int rr = 0; rr < 4; ++rr) {
            const int row_g = r0 + wm + fi * 16 + rg4 * 4 + rr;
            #pragma unroll
            for (int fj = 0; fj < 4; ++fj)
                out[(size_t)row_g * EDIM + j0 + wn + fj * 16 + cl] = acc[fi][fj][rr] + bov[fj];
        }
}

extern "C" void kernel_launch(void* const* d_in, const int* in_sizes, int n_in,
                              void* d_out, int out_size, void* d_ws, size_t ws_size,
                              hipStream_t stream) {
    const float* X  = (const float*)d_in[0];
    const float* Wq = (const float*)d_in[1]; const float* bq = (const float*)d_in[2];
    const float* Wk = (const float*)d_in[3]; const float* bk = (const float*)d_in[4];
    const float* Wv = (const float*)d_in[5]; const float* bv = (const float*)d_in[6];
    const float* Wo = (const float*)d_in[7]; const float* bo = (const float*)d_in[8];
    float* out = (float*)d_out;
    char* base = (char*)d_ws;
    u16*   qf  = (u16*)(base + 0);           // 16*1024*128 bf16 = 4 MB
    u16*   kf  = (u16*)(base + 4194304);     // 4 MB
    u16*   vf  = (u16*)(base + 8388608);     // 2 MB
    float* KVc = (float*)(base + 10485760);  // 16*32*64*128 f32 = 16 MB
    float* K1c = (float*)(base + 27262976);  // 256 KB
    u16*   Spt = (u16*)(base + 27525120);    // 8 MB
    float* K1p = (float*)(base + 35913728);  // 256 KB
    u16*   Amb = (u16*)(base + 36175872);    // 2 MB
    u16*   Xb  = (u16*)(base + 38273024);    // 2 MB
    u16*   Wb  = (u16*)(base + 40370176);    // 4 MB  (total ~44.6 MB)

    hipLaunchKernelGGL(cast_kernel, dim3(2048), dim3(256), 0, stream,
                       X, Wq, Wk, Wv, Wo, Xb, Wb);
    hipLaunchKernelGGL(qkv_mfma_kernel, dim3(16, 4, 3), dim3(256), 0, stream,
                       Xb, Wb, bq, bk, bv, qf, kf, vf);
    {
        const u16* qf_c = qf; const u16* kf_c = kf; const u16* vf_c = vf;
        void* kargs[] = { (void*)&qf_c, (void*)&kf_c, (void*)&vf_c,
                          (void*)&KVc, (void*)&K1c, (void*)&Spt, (void*)&K1p, (void*)&Amb };
        hipLaunchCooperativeKernel((void*)mid_fused_kernel, dim3(512), dim3(256),
                                   kargs, 0, stream);
    }
    hipLaunchKernelGGL(out_mfma_kernel, dim3(16, 4), dim3(256), 0, stream,
                       Amb, Wb + 786432, bo, out);
}

// Round 5
// 110.979 us; speedup vs baseline: 3.3252x; 3.3252x over previous
//
#include <hip/hip_runtime.h>
#include <math.h>

#define LSEQ 1024
#define EDIM 512
#define HD 64
#define CCH 32
#define NCH 32
#define DFEAT 128

typedef unsigned short u16;
typedef short bf16x8 __attribute__((ext_vector_type(8)));
typedef float f32x4 __attribute__((ext_vector_type(4)));

__device__ __forceinline__ u16 f2bf(float f) {
    unsigned u = __float_as_uint(f);
    unsigned r = (u + 0x7fffu + ((u >> 16) & 1u)) >> 16;
    return (u16)r;
}
__device__ __forceinline__ float bf2f(u16 x) {
    return __uint_as_float((unsigned)x << 16);
}
__device__ __forceinline__ void async16(void* lds, const void* g) {
    __builtin_amdgcn_global_load_lds(
        (const __attribute__((address_space(1))) unsigned int*)g,
        (__attribute__((address_space(3))) unsigned int*)lds, 16, 0, 0);
}

// ---------------- cast fp32 -> bf16 for X and the 4 weight matrices
__global__ __launch_bounds__(256) void cast_kernel(
    const float* __restrict__ X,  const float* __restrict__ Wq,
    const float* __restrict__ Wk, const float* __restrict__ Wv,
    const float* __restrict__ Wo, u16* __restrict__ Xb, u16* __restrict__ Wb)
{
    int i = blockIdx.x * 256 + threadIdx.x;   // one float4 group per thread
    const float* src; u16* dst; int off;
    if (i < 262144)      { src = X;  dst = Xb;          off = i; }
    else if (i < 327680) { src = Wq; dst = Wb;          off = i - 262144; }
    else if (i < 393216) { src = Wk; dst = Wb + 262144; off = i - 327680; }
    else if (i < 458752) { src = Wv; dst = Wb + 524288; off = i - 393216; }
    else                 { src = Wo; dst = Wb + 786432; off = i - 458752; }
    float4 v = *(const float4*)&src[(size_t)off * 4];
    ushort4 o; o.x = f2bf(v.x); o.y = f2bf(v.y); o.z = f2bf(v.z); o.w = f2bf(v.w);
    *(ushort4*)&dst[(size_t)off * 4] = o;
}

// ---------------- QKV projection via bf16 MFMA (128x64 tiles, 384 blocks)
__global__ __launch_bounds__(256) void qkv_mfma_kernel(
    const u16* __restrict__ Xb, const u16* __restrict__ Wb,
    const float* __restrict__ bq, const float* __restrict__ bk, const float* __restrict__ bv,
    u16* __restrict__ qf, u16* __restrict__ kf, u16* __restrict__ vf)
{
    const int z = blockIdx.z;
    const u16* __restrict__ W = Wb + (size_t)z * 262144;
    const float* __restrict__ bias = (z == 0) ? bq : (z == 1) ? bk : bv;
    const int r0 = blockIdx.x * 128;
    const int j0 = blockIdx.y * 64;
    __shared__ u16 As[128 * 32];
    __shared__ u16 Bs[64 * 32];
    const int t = threadIdx.x;
    const int wave = t >> 6, lane = t & 63;
    const int cl = lane & 15, rg4 = lane >> 4;
    f32x4 acc[2][4];
    #pragma unroll
    for (int ri = 0; ri < 2; ++ri)
        #pragma unroll
        for (int cj = 0; cj < 4; ++cj) acc[ri][cj] = (f32x4){0.f, 0.f, 0.f, 0.f};

    for (int kb = 0; kb < 512; kb += 32) {
        #pragma unroll
        for (int i = 0; i < 2; ++i) {
            int chunk = i * 256 + t;
            int row = chunk >> 2, kg = chunk & 3;
            async16(&As[(i * 256 + wave * 64) * 8], Xb + (size_t)(r0 + row) * 512 + kb + kg * 8);
        }
        {
            int row = t >> 2, kg = t & 3;
            async16(&Bs[(wave * 64) * 8], W + (size_t)(j0 + row) * 512 + kb + kg * 8);
        }
        __syncthreads();
        bf16x8 af[2], bg[4];
        #pragma unroll
        for (int ri = 0; ri < 2; ++ri)
            af[ri] = *(const bf16x8*)&As[(wave * 32 + ri * 16 + cl) * 32 + rg4 * 8];
        #pragma unroll
        for (int cj = 0; cj < 4; ++cj)
            bg[cj] = *(const bf16x8*)&Bs[(cj * 16 + cl) * 32 + rg4 * 8];
        #pragma unroll
        for (int ri = 0; ri < 2; ++ri)
            #pragma unroll
            for (int cj = 0; cj < 4; ++cj)
                acc[ri][cj] = __builtin_amdgcn_mfma_f32_16x16x32_bf16(af[ri], bg[cj], acc[ri][cj], 0, 0, 0);
        __syncthreads();
    }

    float biasv[4];
    #pragma unroll
    for (int cj = 0; cj < 4; ++cj) biasv[cj] = bias[j0 + cj * 16 + cl];
    const int h = j0 >> 6;
    #pragma unroll
    for (int ri = 0; ri < 2; ++ri) {
        #pragma unroll
        for (int rr = 0; rr < 4; ++rr) {
            const int row_g = r0 + wave * 32 + ri * 16 + rg4 * 4 + rr;
            const int l = row_g >> 1, bb = row_g & 1;
            if (z < 2) {
                float ang = 1.5707963267948966f * (float)(l + 1) * (1.0f / 1024.0f);
                float sv, cv;
                sincosf(ang, &sv, &cv);
                u16* __restrict__ dst = (z == 0) ? qf : kf;
                size_t base = (size_t)((bb * 8 + h) * LSEQ + l) * DFEAT;
                #pragma unroll
                for (int cj = 0; cj < 4; ++cj) {
                    const int d = cj * 16 + cl;
                    float y = fmaxf(acc[ri][cj][rr] + biasv[cj], 0.f);
                    dst[base + d]      = f2bf(y * sv);
                    dst[base + d + 64] = f2bf(y * cv);
                }
            } else {
                size_t base = (size_t)((bb * 8 + h) * LSEQ + l) * HD;
                #pragma unroll
                for (int cj = 0; cj < 4; ++cj) {
                    const int d = cj * 16 + cl;
                    vf[base + d] = f2bf(acc[ri][cj][rr] + biasv[cj]);
                }
            }
        }
    }
}

// ---------------- per-chunk KV sums via MFMA -> bf16 KVc ; fp32 K1 sums
__global__ __launch_bounds__(256) void chunk_sum_kernel(
    const u16* __restrict__ kf, const u16* __restrict__ vf,
    u16* __restrict__ KVc, float* __restrict__ K1c)
{
    const int n = blockIdx.x >> 5;
    const int c = blockIdx.x & 31;
    __shared__ u16 Ks[32 * 128];   // l-major K chunk
    __shared__ u16 KT[128 * 32];   // transposed K
    __shared__ u16 Vs[32 * 64];    // l-major V chunk
    __shared__ u16 VT[64 * 32];    // transposed V
    const int t = threadIdx.x;
    const int wave = t >> 6, lane = t & 63;
    const int cl = lane & 15, rg4 = lane >> 4;
    const u16* kbase = kf + (size_t)(n * LSEQ + c * CCH) * DFEAT;
    const u16* vbase = vf + (size_t)(n * LSEQ + c * CCH) * HD;
    #pragma unroll
    for (int i = 0; i < 2; ++i)
        async16(&Ks[(i * 256 + wave * 64) * 8], kbase + (size_t)(i * 256 + t) * 8);
    async16(&Vs[(wave * 64) * 8], vbase + (size_t)t * 8);
    __syncthreads();
    {   // V transpose
        int m = t & 63, l0 = (t >> 6) * 8;
        u16 tmp[8];
        #pragma unroll
        for (int j = 0; j < 8; ++j) tmp[j] = Vs[(l0 + j) * 64 + m];
        *(bf16x8*)&VT[m * 32 + l0] = *(bf16x8*)tmp;
    }
    {   // K transpose
        int d = t & 127, l0 = (t >> 7) * 16;
        #pragma unroll
        for (int half = 0; half < 2; ++half) {
            u16 tmp[8];
            #pragma unroll
            for (int j = 0; j < 8; ++j) tmp[j] = Ks[(l0 + half * 8 + j) * 128 + d];
            *(bf16x8*)&KT[d * 32 + l0 + half * 8] = *(bf16x8*)tmp;
        }
    }
    __syncthreads();
    // KVc[m][d] = sum_l V[l][m] * K[l][d]
    bf16x8 af = *(const bf16x8*)&VT[(wave * 16 + cl) * 32 + rg4 * 8];
    f32x4 acc[8];
    #pragma unroll
    for (int ni = 0; ni < 8; ++ni) {
        bf16x8 bfr = *(const bf16x8*)&KT[(ni * 16 + cl) * 32 + rg4 * 8];
        acc[ni] = __builtin_amdgcn_mfma_f32_16x16x32_bf16(af, bfr, (f32x4){0.f,0.f,0.f,0.f}, 0, 0, 0);
    }
    u16* outp = KVc + (size_t)(n * NCH + c) * (HD * DFEAT);
    #pragma unroll
    for (int ni = 0; ni < 8; ++ni)
        #pragma unroll
        for (int r = 0; r < 4; ++r)
            outp[(size_t)(wave * 16 + rg4 * 4 + r) * 128 + ni * 16 + cl] = f2bf(acc[ni][r]);
    if (t < 128) {
        float s = 0.f;
        #pragma unroll
        for (int g = 0; g < 4; ++g) {
            bf16x8 kv = *(const bf16x8*)&KT[t * 32 + g * 8];
            #pragma unroll
            for (int j = 0; j < 8; ++j) s += bf2f(((u16*)&kv)[j]);
        }
        K1c[(size_t)(n * NCH + c) * DFEAT + t] = s;
    }
}

// ---------------- exclusive prefix over chunks (bf16 KVc -> bf16 Spt; K1 -> fp32)
__global__ __launch_bounds__(256) void prefix_kernel(
    const u16* __restrict__ KVc, const float* __restrict__ K1c,
    u16* __restrict__ Spt, float* __restrict__ K1p)
{
    const int b = blockIdx.x, t = threadIdx.x;
    const int n = b >> 5;
    const int e = (b & 31) * 256 + t;   // 0..8191 (m*128+d)
    const u16* src = KVc + (size_t)n * NCH * 8192 + e;
    u16* dst = Spt + (size_t)n * NCH * 8192 + e;
    float v[32];
    #pragma unroll
    for (int cc = 0; cc < 32; ++cc) v[cc] = bf2f(src[(size_t)cc * 8192]);
    float run = 0.f;
    #pragma unroll
    for (int cc = 0; cc < 32; ++cc) { dst[(size_t)cc * 8192] = f2bf(run); run += v[cc]; }
    if (b < 8) {
        const int idx = b * 256 + t;  // 0..2047
        const int nn = idx >> 7, d = idx & 127;
        const float* s2 = K1c + (size_t)nn * NCH * DFEAT + d;
        float* d2 = K1p + (size_t)nn * NCH * DFEAT + d;
        float v2[32];
        #pragma unroll
        for (int cc = 0; cc < 32; ++cc) v2[cc] = s2[cc * DFEAT];
        float run2 = 0.f;
        #pragma unroll
        for (int cc = 0; cc < 32; ++cc) { d2[cc * DFEAT] = run2; run2 += v2[cc]; }
    }
}

// ---------------- intra-chunk attention via MFMA + prefix terms + normalize
__global__ __launch_bounds__(256) void attn_kernel(
    const u16* __restrict__ qf, const u16* __restrict__ kf, const u16* __restrict__ vf,
    const u16* __restrict__ Spt, const float* __restrict__ K1p,
    u16* __restrict__ Amb)
{
    const int n = blockIdx.x >> 5;
    const int c = blockIdx.x & 31;
    __shared__ u16 Qs[32 * 136];   // padded rows
    __shared__ u16 Ks[32 * 136];
    __shared__ u16 VT[64 * 32];    // [m][l]
    __shared__ u16 Am[32 * 32];    // masked A, bf16, l-major
    __shared__ float K1s[128];
    __shared__ float dsum2[2][32];
    __shared__ float qk1[32];
    const int t = threadIdx.x;
    const int wave = t >> 6, lane = t & 63;
    const int cl = lane & 15, rg4 = lane >> 4;
    const int mi = wave >> 1, nh = wave & 1;

    const u16* qbase = qf + (size_t)(n * LSEQ + c * CCH) * DFEAT;
    const u16* kbase = kf + (size_t)(n * LSEQ + c * CCH) * DFEAT;
    const u16* vbase = vf + (size_t)(n * LSEQ + c * CCH) * HD;
    const u16* spbase = Spt + (size_t)(n * NCH + c) * 8192;

    // prefetch S_prev B-frags straight from global (16B per lane)
    bf16x8 spf[2][4];
    #pragma unroll
    for (int ni2 = 0; ni2 < 2; ++ni2)
        #pragma unroll
        for (int ks = 0; ks < 4; ++ks)
            spf[ni2][ks] = *(const bf16x8*)&spbase[((2 * nh + ni2) * 16 + cl) * 128 + ks * 32 + rg4 * 8];

    // stage Q,K into padded LDS
    #pragma unroll
    for (int i = 0; i < 2; ++i) {
        int chunk = i * 256 + t;            // 0..511
        int row = chunk >> 4, c8 = chunk & 15;
        *(bf16x8*)&Qs[row * 136 + c8 * 8] = *(const bf16x8*)&qbase[row * 128 + c8 * 8];
        *(bf16x8*)&Ks[row * 136 + c8 * 8] = *(const bf16x8*)&kbase[row * 128 + c8 * 8];
    }
    {   // V transpose (coalesced scalar reads)
        u16 tmp[8];
        #pragma unroll
        for (int j = 0; j < 8; ++j) tmp[j] = vbase[(wave * 8 + j) * HD + lane];
        *(bf16x8*)&VT[lane * 32 + wave * 8] = *(bf16x8*)tmp;
    }
    if (t < 128) K1s[t] = K1p[(size_t)(n * NCH + c) * DFEAT + t];
    __syncthreads();

    // QK^T tile (mi, nh)
    f32x4 a_acc = (f32x4){0.f, 0.f, 0.f, 0.f};
    #pragma unroll
    for (int ks = 0; ks < 4; ++ks) {
        bf16x8 aq = *(const bf16x8*)&Qs[(mi * 16 + cl) * 136 + ks * 32 + rg4 * 8];
        bf16x8 bk = *(const bf16x8*)&Ks[(nh * 16 + cl) * 136 + ks * 32 + rg4 * 8];
        a_acc = __builtin_amdgcn_mfma_f32_16x16x32_bf16(aq, bk, a_acc, 0, 0, 0);
    }
    // mask, fp32 rowsum, write bf16 A
    #pragma unroll
    for (int r = 0; r < 4; ++r) {
        int l_loc = mi * 16 + rg4 * 4 + r;
        int lp_loc = nh * 16 + cl;
        float v = (lp_loc <= l_loc) ? a_acc[r] : 0.f;
        Am[l_loc * 32 + lp_loc] = f2bf(v);
        float s = v;
        s += __shfl_xor(s, 1); s += __shfl_xor(s, 2);
        s += __shfl_xor(s, 4); s += __shfl_xor(s, 8);
        if (cl == 0) dsum2[nh][l_loc] = s;
    }
    {   // q . K1_prev per row: 8 lanes per row, 16 d each
        int row = wave * 8 + (lane >> 3), seg = lane & 7;
        float s = 0.f;
        #pragma unroll
        for (int j = 0; j < 16; ++j) {
            int d = seg * 16 + j;
            s += bf2f(Qs[row * 136 + d]) * K1s[d];
        }
        s += __shfl_xor(s, 1); s += __shfl_xor(s, 2); s += __shfl_xor(s, 4);
        if (seg == 0) qk1[row] = s;
    }
    __syncthreads();

    // C = Q @ S_prev + A_masked @ V
    f32x4 oacc[2] = {(f32x4){0.f,0.f,0.f,0.f}, (f32x4){0.f,0.f,0.f,0.f}};
    #pragma unroll
    for (int ks = 0; ks < 4; ++ks) {
        bf16x8 aq = *(const bf16x8*)&Qs[(mi * 16 + cl) * 136 + ks * 32 + rg4 * 8];
        #pragma unroll
        for (int ni2 = 0; ni2 < 2; ++ni2)
            oacc[ni2] = __builtin_amdgcn_mfma_f32_16x16x32_bf16(aq, spf[ni2][ks], oacc[ni2], 0, 0, 0);
    }
    {
        bf16x8 aa = *(const bf16x8*)&Am[(mi * 16 + cl) * 32 + rg4 * 8];
        #pragma unroll
        for (int ni2 = 0; ni2 < 2; ++ni2) {
            bf16x8 bv = *(const bf16x8*)&VT[((2 * nh + ni2) * 16 + cl) * 32 + rg4 * 8];
            oacc[ni2] = __builtin_amdgcn_mfma_f32_16x16x32_bf16(aa, bv, oacc[ni2], 0, 0, 0);
        }
    }
    // normalize + scatter to Amb
    const int bb = n >> 3, h = n & 7;
    #pragma unroll
    for (int r = 0; r < 4; ++r) {
        int l_loc = mi * 16 + rg4 * 4 + r;
        float den = fmaxf(dsum2[0][l_loc] + dsum2[1][l_loc] + qk1[l_loc], 1e-6f);
        float inv = 1.0f / den;
        int rrow = (c * CCH + l_loc) * 2 + bb;
        #pragma unroll
        for (int ni2 = 0; ni2 < 2; ++ni2) {
            int m = (2 * nh + ni2) * 16 + cl;
            Amb[(size_t)rrow * EDIM + h * 64 + m] = f2bf(oacc[ni2][r] * inv);
        }
    }
}

// ---------------- output projection via bf16 MFMA (64x64 tiles, 256 blocks)
__global__ __launch_bounds__(256) void out_mfma_kernel(
    const u16* __restrict__ Amb, const u16* __restrict__ Wob,
    const float* __restrict__ bo, float* __restrict__ out)
{
    const int r0 = blockIdx.x * 64;
    const int j0 = blockIdx.y * 64;
    __shared__ u16 As[64 * 32];
    __shared__ u16 Bs[64 * 32];
    const int t = threadIdx.x;
    const int wave = t >> 6, lane = t & 63;
    const int cl = lane & 15, rg4 = lane >> 4;
    f32x4 acc[4];
    #pragma unroll
    for (int cj = 0; cj < 4; ++cj) acc[cj] = (f32x4){0.f, 0.f, 0.f, 0.f};

    for (int kb = 0; kb < 512; kb += 32) {
        {
            int row = t >> 2, kg = t & 3;
            async16(&As[(wave * 64) * 8], Amb + (size_t)(r0 + row) * 512 + kb + kg * 8);
            async16(&Bs[(wave * 64) * 8], Wob + (size_t)(j0 + row) * 512 + kb + kg * 8);
        }
        __syncthreads();
        bf16x8 af = *(const bf16x8*)&As[(wave * 16 + cl) * 32 + rg4 * 8];
        bf16x8 bg[4];
        #pragma unroll
        for (int cj = 0; cj < 4; ++cj)
            bg[cj] = *(const bf16x8*)&Bs[(cj * 16 + cl) * 32 + rg4 * 8];
        #pragma unroll
        for (int cj = 0; cj < 4; ++cj)
            acc[cj] = __builtin_amdgcn_mfma_f32_16x16x32_bf16(af, bg[cj], acc[cj], 0, 0, 0);
        __syncthreads();
    }

    float bov[4];
    #pragma unroll
    for (int cj = 0; cj < 4; ++cj) bov[cj] = bo[j0 + cj * 16 + cl];
    #pragma unroll
    for (int rr = 0; rr < 4; ++rr) {
        const int row_g = r0 + wave * 16 + rg4 * 4 + rr;
        #pragma unroll
        for (int cj = 0; cj < 4; ++cj)
            out[(size_t)row_g * EDIM + j0 + cj * 16 + cl] = acc[cj][rr] + bov[cj];
    }
}

extern "C" void kernel_launch(void* const* d_in, const int* in_sizes, int n_in,
                              void* d_out, int out_size, void* d_ws, size_t ws_size,
                              hipStream_t stream) {
    const float* X  = (const float*)d_in[0];
    const float* Wq = (const float*)d_in[1]; const float* bq = (const float*)d_in[2];
    const float* Wk = (const float*)d_in[3]; const float* bk = (const float*)d_in[4];
    const float* Wv = (const float*)d_in[5]; const float* bv = (const float*)d_in[6];
    const float* Wo = (const float*)d_in[7]; const float* bo = (const float*)d_in[8];
    float* out = (float*)d_out;
    char* base = (char*)d_ws;
    u16*   qf  = (u16*)(base + 0);           // 4 MB
    u16*   kf  = (u16*)(base + 4194304);     // 4 MB
    u16*   vf  = (u16*)(base + 8388608);     // 2 MB
    u16*   KVc = (u16*)(base + 10485760);    // 16*32*64*128 bf16 = 8 MB
    float* K1c = (float*)(base + 18874368);  // 256 KB
    u16*   Spt = (u16*)(base + 19136512);    // 8 MB
    float* K1p = (float*)(base + 27525120);  // 256 KB
    u16*   Amb = (u16*)(base + 27787264);    // 2 MB
    u16*   Xb  = (u16*)(base + 29884416);    // 2 MB
    u16*   Wb  = (u16*)(base + 31981568);    // 4 MB (total ~36 MB)

    hipLaunchKernelGGL(cast_kernel, dim3(2048), dim3(256), 0, stream,
                       X, Wq, Wk, Wv, Wo, Xb, Wb);
    hipLaunchKernelGGL(qkv_mfma_kernel, dim3(16, 8, 3), dim3(256), 0, stream,
                       Xb, Wb, bq, bk, bv, qf, kf, vf);
    hipLaunchKernelGGL(chunk_sum_kernel, dim3(512), dim3(256), 0, stream, kf, vf, KVc, K1c);
    hipLaunchKernelGGL(prefix_kernel, dim3(512), dim3(256), 0, stream, KVc, K1c, Spt, K1p);
    hipLaunchKernelGGL(attn_kernel, dim3(512), dim3(256), 0, stream,
                       qf, kf, vf, Spt, K1p, Amb);
    hipLaunchKernelGGL(out_mfma_kernel, dim3(32, 8), dim3(256), 0, stream,
                       Amb, Wb + 786432, bo, out);
}